// Round 4
// baseline (113.753 us; speedup 1.0000x reference)
//
#include <hip/hip_runtime.h>
#include <hip/hip_bf16.h>

#define DEVI __device__ __forceinline__

typedef float f32x4 __attribute__((ext_vector_type(4)));
typedef float float4v __attribute__((ext_vector_type(4)));
typedef __bf16 bf16x8 __attribute__((ext_vector_type(8)));
typedef unsigned short us8 __attribute__((ext_vector_type(8)));

constexpr int NB = 32, TC = 2048, TQ = 256, DD = 256;
constexpr int CR = 64;                      // c-rows per kA block
constexpr float VNEG = -1e29f;

DEVI unsigned short f2bf(float f) {
  unsigned u = __builtin_bit_cast(unsigned, f);
  u += 0x7FFFu + ((u >> 16) & 1u);   // round-to-nearest-even
  return (unsigned short)(u >> 16);
}
DEVI float bf2f(unsigned short h) {
  return __builtin_bit_cast(float, (unsigned)h << 16);
}

// split x = hi + lo (both bf16); dropping lo*lo keeps products at ~2^-18 rel
DEVI void split8(const float* p, us8& h, us8& l) {
#pragma unroll
  for (int i = 0; i < 8; ++i) {
    const float x = p[i];
    const unsigned short hh = f2bf(x);
    h[i] = hh;
    l[i] = f2bf(x - bf2f(hh));
  }
}

// XOR swizzle on 16B granules within a 512B row; involution (write==read).
DEVI int swz(int row, int cb) { return cb ^ (((row ^ (cb >> 7)) & 7) << 4); }

DEVI f32x4 mfma16(us8 a, us8 b, f32x4 c) {
  return __builtin_amdgcn_mfma_f32_16x16x32_bf16(
      __builtin_bit_cast(bf16x8, a), __builtin_bit_cast(bf16x8, b), c, 0, 0, 0);
}

// ---------------------------------------------------------------------------
// P0: precompute Qhi/Qlo (row-major, split-bf16) and QT (transposed bf16 hi).
// blocks [0,512): 64x64 transpose tiles;  blocks [512,640): hi/lo planes.
// ---------------------------------------------------------------------------
__global__ void P0(const float* __restrict__ Qg, unsigned short* __restrict__ Qhi,
                   unsigned short* __restrict__ Qlo, unsigned short* __restrict__ QT)
{
  const int bid = blockIdx.x, tid = threadIdx.x;
  if (bid < 512) {
    __shared__ unsigned short t[64][68];
    const int b = bid >> 4;
    const int q0 = ((bid >> 2) & 3) * 64, d0 = (bid & 3) * 64;
    {
      const int qr = tid >> 2, dp = (tid & 3) * 16;
      const float* src = Qg + ((size_t)b * TQ + q0 + qr) * DD + d0 + dp;
#pragma unroll
      for (int i = 0; i < 16; i += 4) {
        float4v v = *(const float4v*)(src + i);
#pragma unroll
        for (int j = 0; j < 4; ++j) t[qr][dp + i + j] = f2bf(v[j]);
      }
    }
    __syncthreads();
    {
      const int dr = tid >> 2, qp = (tid & 3) * 16;
      us8 a, c;
#pragma unroll
      for (int i = 0; i < 8; ++i) a[i] = t[qp + i][dr];
#pragma unroll
      for (int i = 0; i < 8; ++i) c[i] = t[qp + 8 + i][dr];
      unsigned short* dst = QT + ((size_t)b * DD + d0 + dr) * TQ + q0 + qp;
      *(us8*)dst = a;
      *(us8*)(dst + 8) = c;
    }
  } else {
    const int id = bid - 512;                       // 0..127
    const size_t total = (size_t)NB * TQ * DD;      // 2M elements
    for (size_t base = ((size_t)id * 256 + tid) * 8; base < total;
         base += (size_t)128 * 256 * 8) {
      float v[8];
      *(float4v*)v = *(const float4v*)(Qg + base);
      *(float4v*)(v + 4) = *(const float4v*)(Qg + base + 4);
      us8 h, lo;
      split8(v, h, lo);
      *(us8*)(Qhi + base) = h;
      *(us8*)(Qlo + base) = lo;
    }
  }
}

// ---------------------------------------------------------------------------
// Kernel A: per (batch, 64-row c-tile). 512 threads = 8 waves; wave tile
// 64c x 32q (sim) / 64c x 32d (PV). C tile staged ONCE in LDS (hi/lo,
// swizzled); B-operands (Qhi/Qlo/QT) read from global (L2-resident) with
// double-buffered register prefetch. 4 barriers total.
// ---------------------------------------------------------------------------
__global__ __launch_bounds__(512, 4)
void kA(const float* __restrict__ Cg, const unsigned short* __restrict__ Qhi,
        const unsigned short* __restrict__ Qlo, const unsigned short* __restrict__ QT,
        const int* __restrict__ clenp, const int* __restrict__ qlenp,
        float* __restrict__ out1, float* __restrict__ Mws)
{
  __shared__ __align__(16) char lds[67584];
  char* const bufChi = lds;                 // [64][512B] swizzled (later: P tile)
  char* const bufClo = lds + 32768;         // [64][512B] swizzled
  float* const red = (float*)(lds + 65536); // [8][64]
  char* const bufP = lds;

  const int bid = blockIdx.x;
  const int b = bid & 31;                   // batch -> fixed XCD (bid%8 == b%8)
  const int c0 = (bid >> 5) * CR;
  const int tid = threadIdx.x;
  const int l = tid & 63, wid = tid >> 6;   // 8 waves
  const int g = l >> 4, lm = l & 15;
  const int clen = clenp[b], qlen = qlenp[b];

  const float* Cb = Cg + (size_t)(b * TC + c0) * DD;
  const unsigned short* Qhb = Qhi + (size_t)b * TQ * DD;
  const unsigned short* Qlb = Qlo + (size_t)b * TQ * DD;
  const unsigned short* QTb = QT + (size_t)b * DD * TQ;

  // ---- stage C tile once: 64 rows x 256 d fp32 -> hi/lo bf16 LDS ----
  {
    const int r = tid >> 3;                 // 64 rows, 8 threads/row
    const int d0 = (tid & 7) * 32;
    const float* src = Cb + (size_t)r * DD + d0;
#pragma unroll
    for (int i = 0; i < 4; ++i) {
      float v[8];
      *(float4v*)(v) = *(const float4v*)(src + i * 8);
      *(float4v*)(v + 4) = *(const float4v*)(src + i * 8 + 4);
      us8 h, lo;
      split8(v, h, lo);
      const int cb = (d0 + i * 8) * 2;
      *(us8*)(bufChi + r * 512 + swz(r, cb)) = h;
      *(us8*)(bufClo + r * 512 + swz(r, cb)) = lo;
    }
  }
  __syncthreads();   // barrier 1

  f32x4 acc[4][2];
#pragma unroll
  for (int mt = 0; mt < 4; ++mt)
#pragma unroll
    for (int nt = 0; nt < 2; ++nt) acc[mt][nt] = (f32x4)0.0f;

  // ---- sim: A from LDS, B from global (L2) double-buffered in regs ----
  us8 bh[2][2], bl[2][2];
#pragma unroll
  for (int nt = 0; nt < 2; ++nt) {
    const size_t off = (size_t)(wid * 32 + nt * 16 + lm) * DD + g * 8;
    bh[0][nt] = *(const us8*)(Qhb + off);
    bl[0][nt] = *(const us8*)(Qlb + off);
  }
#pragma unroll
  for (int kk = 0; kk < 8; ++kk) {
    const int cur = kk & 1, nxt = cur ^ 1;
    if (kk < 7) {
#pragma unroll
      for (int nt = 0; nt < 2; ++nt) {
        const size_t off =
            (size_t)(wid * 32 + nt * 16 + lm) * DD + (kk + 1) * 32 + g * 8;
        bh[nxt][nt] = *(const us8*)(Qhb + off);
        bl[nxt][nt] = *(const us8*)(Qlb + off);
      }
    }
    us8 ah[4], al[4];
#pragma unroll
    for (int mt = 0; mt < 4; ++mt) {
      const int row = mt * 16 + lm;
      const int cb = kk * 64 + g * 16;
      ah[mt] = *(const us8*)(bufChi + row * 512 + swz(row, cb));
      al[mt] = *(const us8*)(bufClo + row * 512 + swz(row, cb));
    }
#pragma unroll
    for (int mt = 0; mt < 4; ++mt)
#pragma unroll
      for (int nt = 0; nt < 2; ++nt) {
        acc[mt][nt] = mfma16(ah[mt], bh[cur][nt], acc[mt][nt]);
        acc[mt][nt] = mfma16(ah[mt], bl[cur][nt], acc[mt][nt]);
        acc[mt][nt] = mfma16(al[mt], bh[cur][nt], acc[mt][nt]);
      }
  }

  // ---- mask (exact fp32 absorption to -1e29, as reference) ----
#pragma unroll
  for (int nt = 0; nt < 2; ++nt) {
    const int q = wid * 32 + nt * 16 + lm;
    const bool qm = q >= qlen;
#pragma unroll
    for (int mt = 0; mt < 4; ++mt)
#pragma unroll
      for (int j = 0; j < 4; ++j) {
        const int c = c0 + mt * 16 + g * 4 + j;
        if (qm || c >= clen) acc[mt][nt][j] = VNEG;
      }
  }

  // ---- softmax over q (wave-local shuffle + cross-wave LDS, 8 waves) ----
  float rmax[4][4], rsum[4][4];
#pragma unroll
  for (int mt = 0; mt < 4; ++mt)
#pragma unroll
    for (int j = 0; j < 4; ++j) {
      float m = fmaxf(acc[mt][0][j], acc[mt][1][j]);
      m = fmaxf(m, __shfl_xor(m, 1, 64));
      m = fmaxf(m, __shfl_xor(m, 2, 64));
      m = fmaxf(m, __shfl_xor(m, 4, 64));
      m = fmaxf(m, __shfl_xor(m, 8, 64));
      rmax[mt][j] = m;
    }
  if (lm == 0) {
#pragma unroll
    for (int mt = 0; mt < 4; ++mt)
#pragma unroll
      for (int j = 0; j < 4; ++j)
        red[wid * 64 + mt * 16 + g * 4 + j] = rmax[mt][j];
  }
  __syncthreads();   // barrier 2 (all sim LDS reads done; red-max visible)
#pragma unroll
  for (int mt = 0; mt < 4; ++mt)
#pragma unroll
    for (int j = 0; j < 4; ++j) {
      const int row = mt * 16 + g * 4 + j;
      const float m0 = fmaxf(fmaxf(red[row], red[64 + row]),
                             fmaxf(red[128 + row], red[192 + row]));
      const float m1 = fmaxf(fmaxf(red[256 + row], red[320 + row]),
                             fmaxf(red[384 + row], red[448 + row]));
      rmax[mt][j] = fmaxf(m0, m1);
      if (wid == 0 && lm == 0) Mws[b * TC + c0 + row] = rmax[mt][j];
    }
  // exp + wave partial sums + write P (bf16, un-normalized) into dead C region
#pragma unroll
  for (int mt = 0; mt < 4; ++mt)
#pragma unroll
    for (int j = 0; j < 4; ++j) {
      float s = 0.f;
#pragma unroll
      for (int nt = 0; nt < 2; ++nt) {
        const float p = __expf(acc[mt][nt][j] - rmax[mt][j]);
        acc[mt][nt][j] = p;
        s += p;
      }
      s += __shfl_xor(s, 1, 64);
      s += __shfl_xor(s, 2, 64);
      s += __shfl_xor(s, 4, 64);
      s += __shfl_xor(s, 8, 64);
      rsum[mt][j] = s;
    }
#pragma unroll
  for (int mt = 0; mt < 4; ++mt)
#pragma unroll
    for (int nt = 0; nt < 2; ++nt)
#pragma unroll
      for (int j = 0; j < 4; ++j) {
        const int row = mt * 16 + g * 4 + j;
        const int cb = (wid * 32 + nt * 16 + lm) * 2;
        *(unsigned short*)(bufP + row * 512 + swz(row, cb)) = f2bf(acc[mt][nt][j]);
      }
  __syncthreads();   // barrier 3 (red max-reads done; P visible)
  if (lm == 0) {
#pragma unroll
    for (int mt = 0; mt < 4; ++mt)
#pragma unroll
      for (int j = 0; j < 4; ++j)
        red[wid * 64 + mt * 16 + g * 4 + j] = rsum[mt][j];
  }
  __syncthreads();   // barrier 4
#pragma unroll
  for (int mt = 0; mt < 4; ++mt)
#pragma unroll
    for (int j = 0; j < 4; ++j) {
      const int row = mt * 16 + g * 4 + j;
      const float s0 = (red[row] + red[64 + row]) + (red[128 + row] + red[192 + row]);
      const float s1 = (red[256 + row] + red[320 + row]) + (red[384 + row] + red[448 + row]);
      rsum[mt][j] = s0 + s1;
    }

  // ---- PV: out1 = P @ Q; A from LDS P, B from global QT (L2), prefetched ----
  f32x4 pacc[4][2];
#pragma unroll
  for (int mt = 0; mt < 4; ++mt)
#pragma unroll
    for (int dt = 0; dt < 2; ++dt) pacc[mt][dt] = (f32x4)0.0f;

  us8 qb[2][2];
#pragma unroll
  for (int dt = 0; dt < 2; ++dt) {
    const int d = wid * 32 + dt * 16 + lm;
    qb[0][dt] = *(const us8*)(QTb + (size_t)d * TQ + g * 8);
  }
#pragma unroll
  for (int kq = 0; kq < 8; ++kq) {
    const int cur = kq & 1, nxt = cur ^ 1;
    if (kq < 7) {
#pragma unroll
      for (int dt = 0; dt < 2; ++dt) {
        const int d = wid * 32 + dt * 16 + lm;
        qb[nxt][dt] = *(const us8*)(QTb + (size_t)d * TQ + (kq + 1) * 32 + g * 8);
      }
    }
    us8 pa[4];
#pragma unroll
    for (int mt = 0; mt < 4; ++mt) {
      const int row = mt * 16 + lm;
      pa[mt] = *(const us8*)(bufP + row * 512 + swz(row, kq * 64 + g * 16));
    }
#pragma unroll
    for (int mt = 0; mt < 4; ++mt)
#pragma unroll
      for (int dt = 0; dt < 2; ++dt)
        pacc[mt][dt] = mfma16(pa[mt], qb[cur][dt], pacc[mt][dt]);
  }

  // ---- epilogue ----
#pragma unroll
  for (int mt = 0; mt < 4; ++mt)
#pragma unroll
    for (int j = 0; j < 4; ++j) {
      const float inv = 1.0f / rsum[mt][j];
      const size_t rowoff = (size_t)(b * TC + c0 + mt * 16 + g * 4 + j) * DD;
#pragma unroll
      for (int dt = 0; dt < 2; ++dt)
        out1[rowoff + wid * 32 + dt * 16 + lm] = pacc[mt][dt][j] * inv;
    }
}

// ---------------------------------------------------------------------------
// Kernel B1: per-batch max + softmax denominator over M[b, 0..TC)
// ---------------------------------------------------------------------------
__global__ void kB1(const float* __restrict__ Mws, float* __restrict__ bmax,
                    float* __restrict__ bden)
{
  const int b = blockIdx.x, tid = threadIdx.x;
  __shared__ float sred[8];
  const float* Mb = Mws + b * TC;
  float m = -3.4e38f;
  for (int i = tid; i < TC; i += 256) m = fmaxf(m, Mb[i]);
  m = fmaxf(m, __shfl_xor(m, 1, 64));  m = fmaxf(m, __shfl_xor(m, 2, 64));
  m = fmaxf(m, __shfl_xor(m, 4, 64));  m = fmaxf(m, __shfl_xor(m, 8, 64));
  m = fmaxf(m, __shfl_xor(m, 16, 64)); m = fmaxf(m, __shfl_xor(m, 32, 64));
  const int w = tid >> 6;
  if ((tid & 63) == 0) sred[w] = m;
  __syncthreads();
  m = fmaxf(fmaxf(sred[0], sred[1]), fmaxf(sred[2], sred[3]));
  float s = 0.f;
  for (int i = tid; i < TC; i += 256) s += __expf(Mb[i] - m);
  s += __shfl_xor(s, 1, 64);  s += __shfl_xor(s, 2, 64);
  s += __shfl_xor(s, 4, 64);  s += __shfl_xor(s, 8, 64);
  s += __shfl_xor(s, 16, 64); s += __shfl_xor(s, 32, 64);
  if ((tid & 63) == 0) sred[4 + w] = s;
  __syncthreads();
  if (tid == 0) { bmax[b] = m; bden[b] = (sred[4] + sred[5]) + (sred[6] + sred[7]); }
}

// ---------------------------------------------------------------------------
// Kernel B2: part[b,chunk,d] = sum_{c in chunk} softmax(M)[c] * C[b,c,d]
// ---------------------------------------------------------------------------
__global__ void kB2(const float* __restrict__ Cg, const float* __restrict__ Mws,
                    const float* __restrict__ bmax, const float* __restrict__ bden,
                    float* __restrict__ part)
{
  const int b = blockIdx.x >> 4;
  const int ch = blockIdx.x & 15;
  const int cbase = ch * 128;
  const int tid = threadIdx.x;                // = d
  __shared__ float w[128];
  const float bm = bmax[b];
  const float invd = 1.0f / bden[b];
  if (tid < 128) w[tid] = __expf(Mws[b * TC + cbase + tid] - bm) * invd;
  __syncthreads();
  float acc = 0.f;
  const float* Cb = Cg + (size_t)(b * TC + cbase) * DD + tid;
#pragma unroll 4
  for (int c = 0; c < 128; ++c) acc += w[c] * Cb[(size_t)c * DD];
  part[((size_t)b * 16 + ch) * DD + tid] = acc;
}

// ---------------------------------------------------------------------------
// Kernel C (fused B3): q2c[b,d] = sum_ch part, broadcast -> out2[b, c-seg, d]
// ---------------------------------------------------------------------------
__global__ void kC(const float* __restrict__ part, float* __restrict__ out2)
{
  const int b = blockIdx.x >> 4, seg = blockIdx.x & 15;
  const int d = threadIdx.x;
  float s = 0.f;
#pragma unroll
  for (int ch = 0; ch < 16; ++ch) s += part[((size_t)b * 16 + ch) * DD + d];
  float* dst = out2 + ((size_t)b * TC + seg * 128) * DD + d;
#pragma unroll 4
  for (int c = 0; c < 128; ++c) dst[(size_t)c * DD] = s;
}

extern "C" void kernel_launch(void* const* d_in, const int* in_sizes, int n_in,
                              void* d_out, int out_size, void* d_ws, size_t ws_size,
                              hipStream_t stream)
{
  const float* Cg = (const float*)d_in[0];
  const float* Qg = (const float*)d_in[1];
  const int* clen = (const int*)d_in[2];
  const int* qlen = (const int*)d_in[3];
  float* out1 = (float*)d_out;
  float* out2 = out1 + (size_t)NB * TC * DD;

  char* ws = (char*)d_ws;
  float* Mws  = (float*)(ws);                         // 32*2048 f32   = 256 KB
  float* part = (float*)(ws + 262144);                // 32*16*256 f32 = 512 KB
  float* bmax = (float*)(ws + 786432);                // 32 f32
  float* bden = (float*)(ws + 786560);                // 32 f32
  unsigned short* Qhi = (unsigned short*)(ws + 786688);        // 4 MB
  unsigned short* Qlo = (unsigned short*)(ws + 786688 + 4194304);
  unsigned short* QT  = (unsigned short*)(ws + 786688 + 8388608);

  P0 <<<dim3(640), dim3(256), 0, stream>>>(Qg, Qhi, Qlo, QT);
  kA <<<dim3(NB * (TC / CR)), dim3(512), 0, stream>>>(Cg, Qhi, Qlo, QT, clen, qlen,
                                                      out1, Mws);
  kB1<<<dim3(NB), dim3(256), 0, stream>>>(Mws, bmax, bden);
  kB2<<<dim3(NB * 16), dim3(256), 0, stream>>>(Cg, Mws, bmax, bden, part);
  kC <<<dim3(NB * 16), dim3(256), 0, stream>>>(part, out2);
}

// Round 5
// 94.032 us; speedup vs baseline: 1.2097x; 1.2097x over previous
//
#include <hip/hip_runtime.h>
#include <hip/hip_fp16.h>

#define DEVI __device__ __forceinline__

typedef float f32x4 __attribute__((ext_vector_type(4)));
typedef float float4v __attribute__((ext_vector_type(4)));
typedef _Float16 f16x8 __attribute__((ext_vector_type(8)));
typedef unsigned short us8 __attribute__((ext_vector_type(8)));

constexpr int NB = 32, TC = 2048, TQ = 256, DD = 256;
constexpr int CR = 64;                      // c-rows per kA block
constexpr float VNEG = -1e29f;

DEVI unsigned short f2h(float f) {
  _Float16 h = (_Float16)f;                 // v_cvt_f16_f32 (RN)
  return __builtin_bit_cast(unsigned short, h);
}
DEVI float h2f(unsigned short u) {
  return (float)__builtin_bit_cast(_Float16, u);
}

// XOR swizzle on 16B granules within a 512B row; involution (write==read).
// Low 4 bits pass through, so it is valid for unaligned 2B element offsets too.
DEVI int swz(int row, int cb) { return cb ^ (((row ^ (cb >> 7)) & 7) << 4); }

DEVI f32x4 mfmah(us8 a, us8 b, f32x4 c) {
  return __builtin_amdgcn_mfma_f32_16x16x32_f16(
      __builtin_bit_cast(f16x8, a), __builtin_bit_cast(f16x8, b), c, 0, 0, 0);
}

// ---------------------------------------------------------------------------
// P0: one pass over Q producing Qh (fp16 row-major) AND QT (fp16 transposed).
// 512 blocks: one 64x64 tile each.
// ---------------------------------------------------------------------------
__global__ void P0(const float* __restrict__ Qg, unsigned short* __restrict__ Qh,
                   unsigned short* __restrict__ QT)
{
  __shared__ unsigned short t[64][72];
  const int bid = blockIdx.x, tid = threadIdx.x;
  const int b = bid >> 4;
  const int q0 = ((bid >> 2) & 3) * 64, d0 = (bid & 3) * 64;
  {
    const int qr = tid >> 2, dp = (tid & 3) * 16;
    const float* src = Qg + ((size_t)b * TQ + q0 + qr) * DD + d0 + dp;
    unsigned short* dst = Qh + ((size_t)b * TQ + q0 + qr) * DD + d0 + dp;
    us8 o0, o1;
#pragma unroll
    for (int i = 0; i < 4; ++i) {
      float4v v = *(const float4v*)(src + i * 4);
#pragma unroll
      for (int j = 0; j < 4; ++j) {
        const unsigned short h = f2h(v[j]);
        t[qr][dp + i * 4 + j] = h;
        if (i < 2) o0[i * 4 + j] = h; else o1[(i - 2) * 4 + j] = h;
      }
    }
    *(us8*)dst = o0;
    *(us8*)(dst + 8) = o1;
  }
  __syncthreads();
  {
    const int dr = tid >> 2, qp = (tid & 3) * 16;
    us8 a, c;
#pragma unroll
    for (int i = 0; i < 8; ++i) a[i] = t[qp + i][dr];
#pragma unroll
    for (int i = 0; i < 8; ++i) c[i] = t[qp + 8 + i][dr];
    unsigned short* dst = QT + ((size_t)b * DD + d0 + dr) * TQ + q0 + qp;
    *(us8*)dst = a;
    *(us8*)(dst + 8) = c;
  }
}

// ---------------------------------------------------------------------------
// Kernel A: per (batch, 64-row c-tile), 256 threads = 4 waves (wave = 64c x
// 64q / 64c x 64d). fp16 MFMA for sim and PV. C staged once in LDS (fp16,
// swizzled); Q operands from global (L2-resident) with register prefetch.
// Also emits the q2c per-tile partials (pnum/ptM/ptD) from the LDS C-tile.
// ---------------------------------------------------------------------------
__global__ __launch_bounds__(256, 4)
void kA(const float* __restrict__ Cg, const unsigned short* __restrict__ Qh,
        const unsigned short* __restrict__ QT,
        const int* __restrict__ clenp, const int* __restrict__ qlenp,
        float* __restrict__ out1, float* __restrict__ pnum,
        float* __restrict__ ptM, float* __restrict__ ptD)
{
  __shared__ __align__(16) char lds[32768];  // bufC (fp16), later bufP
  __shared__ float red[256];                 // [4 waves][64 rows]
  __shared__ float wred[64];                 // row max M_c
  __shared__ float wexp[64];                 // exp(M_c - mtile)
  char* const bufC = lds;
  char* const bufP = lds;

  const int bid = blockIdx.x;
  const int b = bid & 31;                   // batch -> fixed XCD (bid%8 == b%8)
  const int tile = bid >> 5;                // 0..31
  const int c0 = tile * CR;
  const int tid = threadIdx.x;
  const int l = tid & 63, wid = tid >> 6;   // 4 waves
  const int g = l >> 4, lm = l & 15;
  const int clen = clenp[b], qlen = qlenp[b];

  const float* Cb = Cg + (size_t)(b * TC + c0) * DD;
  const unsigned short* Qhb = Qh + (size_t)b * TQ * DD;
  const unsigned short* QTb = QT + (size_t)b * DD * TQ;

  // ---- stage C tile once: 64 rows x 256 d fp32 -> fp16 LDS ----
  {
    const int r = tid >> 2;
    const int d0 = (tid & 3) * 64;
    const float* src = Cb + (size_t)r * DD + d0;
#pragma unroll
    for (int i = 0; i < 8; ++i) {
      us8 h;
#pragma unroll
      for (int k = 0; k < 8; k += 4) {
        float4v v = *(const float4v*)(src + i * 8 + k);
#pragma unroll
        for (int j = 0; j < 4; ++j) h[k + j] = f2h(v[j]);
      }
      *(us8*)(bufC + r * 512 + swz(r, (d0 + i * 8) * 2)) = h;
    }
  }
  __syncthreads();   // bar1

  f32x4 acc[4][4];
#pragma unroll
  for (int mt = 0; mt < 4; ++mt)
#pragma unroll
    for (int nt = 0; nt < 4; ++nt) acc[mt][nt] = (f32x4)0.0f;

  // ---- sim: A (C rows) from LDS, B (Q rows) from global, prefetched ----
  us8 bh[2][4];
#pragma unroll
  for (int nt = 0; nt < 4; ++nt)
    bh[0][nt] = *(const us8*)(Qhb + (size_t)(wid * 64 + nt * 16 + lm) * DD + g * 8);
#pragma unroll
  for (int kk = 0; kk < 8; ++kk) {
    const int cur = kk & 1, nxt = cur ^ 1;
    if (kk < 7) {
#pragma unroll
      for (int nt = 0; nt < 4; ++nt)
        bh[nxt][nt] = *(const us8*)(Qhb + (size_t)(wid * 64 + nt * 16 + lm) * DD +
                                    (kk + 1) * 32 + g * 8);
    }
    us8 ah[4];
#pragma unroll
    for (int mt = 0; mt < 4; ++mt) {
      const int row = mt * 16 + lm;
      ah[mt] = *(const us8*)(bufC + row * 512 + swz(row, kk * 64 + g * 16));
    }
#pragma unroll
    for (int mt = 0; mt < 4; ++mt)
#pragma unroll
      for (int nt = 0; nt < 4; ++nt)
        acc[mt][nt] = mfmah(ah[mt], bh[cur][nt], acc[mt][nt]);
  }

  // ---- mask (exact fp32 absorption to -1e29, as reference) ----
#pragma unroll
  for (int nt = 0; nt < 4; ++nt) {
    const int q = wid * 64 + nt * 16 + lm;
    const bool qm = q >= qlen;
#pragma unroll
    for (int mt = 0; mt < 4; ++mt)
#pragma unroll
      for (int j = 0; j < 4; ++j) {
        const int c = c0 + mt * 16 + g * 4 + j;
        if (qm || c >= clen) acc[mt][nt][j] = VNEG;
      }
  }

  // ---- softmax over q ----
  float rmax[4][4], rsum[4][4];
#pragma unroll
  for (int mt = 0; mt < 4; ++mt)
#pragma unroll
    for (int j = 0; j < 4; ++j) {
      float m = fmaxf(fmaxf(acc[mt][0][j], acc[mt][1][j]),
                      fmaxf(acc[mt][2][j], acc[mt][3][j]));
      m = fmaxf(m, __shfl_xor(m, 1, 64));
      m = fmaxf(m, __shfl_xor(m, 2, 64));
      m = fmaxf(m, __shfl_xor(m, 4, 64));
      m = fmaxf(m, __shfl_xor(m, 8, 64));
      rmax[mt][j] = m;
    }
  if (lm == 0) {
#pragma unroll
    for (int mt = 0; mt < 4; ++mt)
#pragma unroll
      for (int j = 0; j < 4; ++j)
        red[wid * 64 + mt * 16 + g * 4 + j] = rmax[mt][j];
  }
  __syncthreads();   // bar2
#pragma unroll
  for (int mt = 0; mt < 4; ++mt)
#pragma unroll
    for (int j = 0; j < 4; ++j) {
      const int row = mt * 16 + g * 4 + j;
      rmax[mt][j] = fmaxf(fmaxf(red[row], red[64 + row]),
                          fmaxf(red[128 + row], red[192 + row]));
      if (wid == 0 && lm == 0) wred[row] = rmax[mt][j];
    }
  // tile max (over all 64 rows): local 16 rows then across g
  float mtile;
  {
    float m = rmax[0][0];
#pragma unroll
    for (int mt = 0; mt < 4; ++mt)
#pragma unroll
      for (int j = 0; j < 4; ++j) m = fmaxf(m, rmax[mt][j]);
    m = fmaxf(m, __shfl_xor(m, 16, 64));
    m = fmaxf(m, __shfl_xor(m, 32, 64));
    mtile = m;
  }
  // exp + wave partial sums
#pragma unroll
  for (int mt = 0; mt < 4; ++mt)
#pragma unroll
    for (int j = 0; j < 4; ++j) {
      float s = 0.f;
#pragma unroll
      for (int nt = 0; nt < 4; ++nt) {
        const float p = __expf(acc[mt][nt][j] - rmax[mt][j]);
        acc[mt][nt][j] = p;
        s += p;
      }
      s += __shfl_xor(s, 1, 64);
      s += __shfl_xor(s, 2, 64);
      s += __shfl_xor(s, 4, 64);
      s += __shfl_xor(s, 8, 64);
      rsum[mt][j] = s;
    }
  __syncthreads();   // bar3 (red-max reads done; wred visible)
  if (lm == 0) {
#pragma unroll
    for (int mt = 0; mt < 4; ++mt)
#pragma unroll
      for (int j = 0; j < 4; ++j)
        red[wid * 64 + mt * 16 + g * 4 + j] = rsum[mt][j];
  }
  if (wid == 0) {
    const float wv = __expf(wred[l] - mtile);
    wexp[l] = wv;
    float s = wv;
    s += __shfl_xor(s, 1, 64);  s += __shfl_xor(s, 2, 64);
    s += __shfl_xor(s, 4, 64);  s += __shfl_xor(s, 8, 64);
    s += __shfl_xor(s, 16, 64); s += __shfl_xor(s, 32, 64);
    if (l == 0) { ptD[b * 32 + tile] = s; ptM[b * 32 + tile] = mtile; }
  }
  __syncthreads();   // bar4 (red-sum + wexp visible)
#pragma unroll
  for (int mt = 0; mt < 4; ++mt)
#pragma unroll
    for (int j = 0; j < 4; ++j) {
      const int row = mt * 16 + g * 4 + j;
      rsum[mt][j] = (red[row] + red[64 + row]) + (red[128 + row] + red[192 + row]);
    }

  // ---- q2c partial from LDS C-tile: pnum[d] = sum_r wexp[r]*C[r,d] ----
  {
    float qacc = 0.f;
    const int d2 = tid * 2;
#pragma unroll 8
    for (int r = 0; r < 64; ++r) {
      const float cv = h2f(*(const unsigned short*)(bufC + r * 512 + swz(r, d2)));
      qacc += wexp[r] * cv;
    }
    pnum[((size_t)b * 32 + tile) * DD + tid] = qacc;
  }
  __syncthreads();   // bar5 (bufC reads done; safe to overwrite with P)

  // ---- write P (un-normalized exp, fp16) into bufP (aliases bufC) ----
#pragma unroll
  for (int mt = 0; mt < 4; ++mt)
#pragma unroll
    for (int nt = 0; nt < 4; ++nt)
#pragma unroll
      for (int j = 0; j < 4; ++j) {
        const int row = mt * 16 + g * 4 + j;
        const int cb = (wid * 64 + nt * 16 + lm) * 2;
        *(unsigned short*)(bufP + row * 512 + swz(row, cb)) = f2h(acc[mt][nt][j]);
      }
  __syncthreads();   // bar6 (P visible)

  // ---- PV: out1 = P @ Q; A from LDS P, B from global QT, prefetched ----
  f32x4 pacc[4][4];
#pragma unroll
  for (int mt = 0; mt < 4; ++mt)
#pragma unroll
    for (int dt = 0; dt < 4; ++dt) pacc[mt][dt] = (f32x4)0.0f;

  us8 qb[2][4];
#pragma unroll
  for (int dt = 0; dt < 4; ++dt)
    qb[0][dt] = *(const us8*)(QTb + (size_t)(wid * 64 + dt * 16 + lm) * TQ + g * 8);
#pragma unroll
  for (int kq = 0; kq < 8; ++kq) {
    const int cur = kq & 1, nxt = cur ^ 1;
    if (kq < 7) {
#pragma unroll
      for (int dt = 0; dt < 4; ++dt)
        qb[nxt][dt] = *(const us8*)(QTb + (size_t)(wid * 64 + dt * 16 + lm) * TQ +
                                    (kq + 1) * 32 + g * 8);
    }
    us8 pa[4];
#pragma unroll
    for (int mt = 0; mt < 4; ++mt) {
      const int row = mt * 16 + lm;
      pa[mt] = *(const us8*)(bufP + row * 512 + swz(row, kq * 64 + g * 16));
    }
#pragma unroll
    for (int mt = 0; mt < 4; ++mt)
#pragma unroll
      for (int dt = 0; dt < 4; ++dt)
        pacc[mt][dt] = mfmah(pa[mt], qb[cur][dt], pacc[mt][dt]);
  }

  // ---- epilogue: normalize and store ----
#pragma unroll
  for (int mt = 0; mt < 4; ++mt)
#pragma unroll
    for (int j = 0; j < 4; ++j) {
      const float inv = 1.0f / rsum[mt][j];
      const size_t rowoff = (size_t)(b * TC + c0 + mt * 16 + g * 4 + j) * DD;
#pragma unroll
      for (int dt = 0; dt < 4; ++dt)
        out1[rowoff + wid * 64 + dt * 16 + lm] = pacc[mt][dt][j] * inv;
    }
}

// ---------------------------------------------------------------------------
// kComb: q2c[b,d] = sum_t e^{ptM_t - m} pnum[t,d] / (sum_t e^{ptM_t - m} ptD_t)
// ---------------------------------------------------------------------------
__global__ void kComb(const float* __restrict__ pnum, const float* __restrict__ ptM,
                      const float* __restrict__ ptD, float* __restrict__ q2c)
{
  const int b = blockIdx.x, tid = threadIdx.x;
  __shared__ float sM[32], sD[32];
  if (tid < 32) { sM[tid] = ptM[b * 32 + tid]; sD[tid] = ptD[b * 32 + tid]; }
  __syncthreads();
  float m = sM[0];
#pragma unroll
  for (int t = 1; t < 32; ++t) m = fmaxf(m, sM[t]);
  float den = 0.f, acc = 0.f;
#pragma unroll
  for (int t = 0; t < 32; ++t) {
    const float sc = __expf(sM[t] - m);
    den += sc * sD[t];
    acc += sc * pnum[((size_t)b * 32 + t) * DD + tid];
  }
  q2c[b * DD + tid] = acc / den;
}

// ---------------------------------------------------------------------------
// kC: broadcast q2c[b,d] -> out2[b, c-seg, d]
// ---------------------------------------------------------------------------
__global__ void kC(const float* __restrict__ q2c, float* __restrict__ out2)
{
  const int b = blockIdx.x >> 4, seg = blockIdx.x & 15;
  const int d = threadIdx.x;
  const float s = q2c[b * DD + d];
  float* dst = out2 + ((size_t)b * TC + seg * 128) * DD + d;
#pragma unroll 4
  for (int c = 0; c < 128; ++c) dst[(size_t)c * DD] = s;
}

extern "C" void kernel_launch(void* const* d_in, const int* in_sizes, int n_in,
                              void* d_out, int out_size, void* d_ws, size_t ws_size,
                              hipStream_t stream)
{
  const float* Cg = (const float*)d_in[0];
  const float* Qg = (const float*)d_in[1];
  const int* clen = (const int*)d_in[2];
  const int* qlen = (const int*)d_in[3];
  float* out1 = (float*)d_out;
  float* out2 = out1 + (size_t)NB * TC * DD;

  char* ws = (char*)d_ws;
  float* pnum = (float*)(ws);                          // 32*32*256 f32 = 1 MB
  float* ptM  = (float*)(ws + 1048576);                // 1024 f32
  float* ptD  = (float*)(ws + 1052672);                // 1024 f32
  float* q2c  = (float*)(ws + 1056768);                // 32*256 f32
  unsigned short* Qh = (unsigned short*)(ws + 1089536);          // 4 MB
  unsigned short* QT = (unsigned short*)(ws + 1089536 + 4194304);// 4 MB

  P0   <<<dim3(512), dim3(256), 0, stream>>>(Qg, Qh, QT);
  kA   <<<dim3(NB * (TC / CR)), dim3(256), 0, stream>>>(Cg, Qh, QT, clen, qlen,
                                                        out1, pnum, ptM, ptD);
  kComb<<<dim3(NB), dim3(256), 0, stream>>>(pnum, ptM, ptD, q2c);
  kC   <<<dim3(NB * 16), dim3(256), 0, stream>>>(q2c, out2);
}